// Round 5
// baseline (141.591 us; speedup 1.0000x reference)
//
#include <hip/hip_runtime.h>
#include <cstdint>
#include <cstddef>

// RoGPE node encoder. 6 kernels:
//  k0 pack_w: W0/W1/W2 -> bf16 hi/lo MFMA B-fragments, packed for coalesced
//             16B/lane loads (done ONCE, kills per-block split8 VALU + i-cache)
//  k1 mlp_mfma: zero A/s1/ws2 + 3-layer MLP via bf16 hi/lo split MFMA
//               (3-term compensation) + fused W3 dot -> a0.
//               8 nodes/block x 512 blocks = 2 blocks/CU (R4 was 1/CU, 93% stall)
//  k2 build_graph: s1[r] += ln2*a0[c] (dupes kept), A bitset atomicOr
//  k3 a1_ws: a1 = a0+s1; ws1[w] = per-64-word sums (direct store)
//  k4 hop2: A2 row = OR of neighbor A rows; s2 = s1+ln3*(A2@a1); a2=a1+s2
//  k5 hop3: A3 row on the fly from A2; out = a2 + s2 + ln4*(A3@a2)

constexpr int NN   = 4096;
constexpr int D    = 128;
constexpr int NE   = 131072;
constexpr int WPR  = 64;    // u64 words per bitset row
constexpr int MAXN = 256;   // neighbor-list cap (deg ~Binom, mean 32, max ~64)

typedef __attribute__((ext_vector_type(8))) short  short8;
typedef __attribute__((ext_vector_type(4))) float  float4v;

__device__ __forceinline__ unsigned short f32_bf16(float x) {
  unsigned u = __float_as_uint(x);
  return (unsigned short)((u + 0x7FFFu + ((u >> 16) & 1u)) >> 16);  // RNE
}
__device__ __forceinline__ float bf16_f32(unsigned short b) {
  return __uint_as_float(((unsigned)b) << 16);
}

struct Frag { short8 hi; short8 lo; };

// 8 consecutive floats (16B-aligned) -> bf16 hi/lo split fragments
__device__ __forceinline__ Frag split8(const float* __restrict__ p) {
  float4v a = *(const float4v*)p;
  float4v b = *(const float4v*)(p + 4);
  Frag f;
#pragma unroll
  for (int j = 0; j < 4; ++j) {
    float x = a[j];
    unsigned short h = f32_bf16(x);
    f.hi[j] = (short)h;
    f.lo[j] = (short)f32_bf16(x - bf16_f32(h));
    float y = b[j];
    unsigned short h2 = f32_bf16(y);
    f.hi[j + 4] = (short)h2;
    f.lo[j + 4] = (short)f32_bf16(y - bf16_f32(h2));
  }
  return f;
}

// 3-term compensated product (lo*lo dropped; R3 vs R4 absmax identical)
__device__ __forceinline__ float4v mfma3(const Frag& A, const Frag& B, float4v c) {
  c = __builtin_amdgcn_mfma_f32_16x16x32_bf16(A.lo, B.hi, c, 0, 0, 0);
  c = __builtin_amdgcn_mfma_f32_16x16x32_bf16(A.hi, B.lo, c, 0, 0, 0);
  c = __builtin_amdgcn_mfma_f32_16x16x32_bf16(A.hi, B.hi, c, 0, 0, 0);
  return c;
}

__device__ __forceinline__ float wave_sum64(float v) {
#pragma unroll
  for (int off = 32; off >= 1; off >>= 1) v += __shfl_xor(v, off, 64);
  return v;
}

// ---------------- k0: pack weights into MFMA B-fragments ----------------
// Fragment block (L, o, kt) = 1024 shorts: [0..511] hi (lane*8), [512..1023] lo.
// B-frag element: W_L[(o*16 + l16)*128 + kt*32 + quad*8 + j], j=0..7.
// One wave covers exactly one (L,o,kt) block -> hi write = contiguous 1 KB.
__global__ __launch_bounds__(256) void pack_w(
    const float* __restrict__ W0, const float* __restrict__ W1,
    const float* __restrict__ W2, short* __restrict__ Wp) {
  int tid = blockIdx.x * 256 + threadIdx.x;  // 6144 total
  int lane = tid & 63, kt = (tid >> 6) & 3, o = (tid >> 8) & 7, L = tid >> 11;
  int quad = lane >> 4, l16 = lane & 15;
  const float* W = (L == 0) ? W0 : (L == 1) ? W1 : W2;
  Frag f = split8(W + (size_t)(o * 16 + l16) * D + kt * 32 + quad * 8);
  short* base = Wp + (size_t)(((L * 8 + o) * 4) + kt) * 1024;
  *(short8*)(base + lane * 8) = f.hi;
  *(short8*)(base + 512 + lane * 8) = f.lo;
}

// ---------------- k1: zero-init + MFMA MLP ----------------
// 512 blocks x 256 threads, 8 nodes/block (A rows 8..15 duplicate 0..7 —
// MFMA waste is free at 1% util; 2 blocks/CU doubles latency hiding).
// A-frag: A[m=lane&15][k=quad*8+j]; B-frag from packed Wp; C/D: row=quad*4+reg,
// col=lane&15.
__global__ __launch_bounds__(256) void mlp_mfma(
    const float* __restrict__ coeffs, const short* __restrict__ Wp,
    const float* __restrict__ b0,
    const float* __restrict__ W3, const float* __restrict__ b3,
    float* __restrict__ a0v,
    unsigned long long* __restrict__ A, float* __restrict__ s1,
    float* __restrict__ ws2) {
  __shared__ float hbuf[16 * 132];
  __shared__ float psh[4][16];
  const int b = blockIdx.x, t = threadIdx.x;
  const int wave = t >> 6, lane = t & 63;
  const int quad = lane >> 4, l16 = lane & 15;
  const int node0 = b * 8;
  const int ot0 = 2 * wave, ot1 = 2 * wave + 1;

  // zero A slice (4 KB/block), s1 slice (8 f), ws2 (64 f, block 0)
  {
    float4v z4 = {0.f, 0.f, 0.f, 0.f};
    ((float4v*)A)[(size_t)b * 256 + t] = z4;
    if (t < 2) ((float4v*)(s1 + node0))[t] = z4;
    if (b == 0 && t < 16) ((float4v*)ws2)[t] = z4;
  }

  float4v r0, r1;
#pragma unroll
  for (int L = 0; L < 3; ++L) {
    Frag Af[4];
    const float* abase = (L == 0)
        ? coeffs + (size_t)(node0 + (l16 & 7)) * D + quad * 8
        : hbuf + (l16 & 7) * 132 + quad * 8;
#pragma unroll
    for (int kt = 0; kt < 4; ++kt) Af[kt] = split8(abase + kt * 32);
    const short* WL = Wp + (size_t)L * 8 * 4 * 1024;
    float4v acc0 = {0.f, 0.f, 0.f, 0.f}, acc1 = acc0;
#pragma unroll
    for (int kt = 0; kt < 4; ++kt) {
      const short* p0 = WL + (size_t)(ot0 * 4 + kt) * 1024 + lane * 8;
      const short* p1 = WL + (size_t)(ot1 * 4 + kt) * 1024 + lane * 8;
      Frag B0, B1;
      B0.hi = *(const short8*)p0;
      B0.lo = *(const short8*)(p0 + 512);
      B1.hi = *(const short8*)p1;
      B1.lo = *(const short8*)(p1 + 512);
      acc0 = mfma3(Af[kt], B0, acc0);
      acc1 = mfma3(Af[kt], B1, acc1);
    }
    if (L == 0) {
      float ba = b0[ot0 * 16 + l16], bb = b0[ot1 * 16 + l16];
#pragma unroll
      for (int j = 0; j < 4; ++j) { acc0[j] += ba; acc1[j] += bb; }
    }
#pragma unroll
    for (int j = 0; j < 4; ++j) {
      acc0[j] = fmaxf(acc0[j], 0.f);
      acc1[j] = fmaxf(acc1[j], 0.f);
    }
    if (L < 2) {
      __syncthreads();  // all hbuf A-frag reads done before overwrite
#pragma unroll
      for (int j = 0; j < 4; ++j) {
        hbuf[(quad * 4 + j) * 132 + ot0 * 16 + l16] = acc0[j];
        hbuf[(quad * 4 + j) * 132 + ot1 * 16 + l16] = acc1[j];
      }
      __syncthreads();
    } else {
      r0 = acc0; r1 = acc1;
    }
  }
  // fused 128->1 dot with W3
  float w3a = W3[ot0 * 16 + l16], w3b = W3[ot1 * 16 + l16];
#pragma unroll
  for (int j = 0; j < 4; ++j) {
    float v = fmaf(r0[j], w3a, r1[j] * w3b);
#pragma unroll
    for (int off = 1; off <= 8; off <<= 1) v += __shfl_xor(v, off, 64);
    if (l16 == 0) psh[wave][quad * 4 + j] = v;
  }
  __syncthreads();
  if (t < 8)
    a0v[node0 + t] = psh[0][t] + psh[1][t] + psh[2][t] + psh[3][t] + b3[0];
}

// ---------------- k2: bitset adjacency + hop-1 scatter ----------------
__global__ __launch_bounds__(256) void build_graph(
    const int* __restrict__ er, const int* __restrict__ ec,
    const float* __restrict__ a0, unsigned long long* __restrict__ A,
    float* __restrict__ s1) {
  int e = blockIdx.x * 256 + threadIdx.x;
  if (e >= NE) return;
  int r = er[e] & (NN - 1);
  int c = ec[e] & (NN - 1);
  atomicOr(&A[(size_t)r * WPR + (c >> 6)], 1ull << (c & 63));
  atomicAdd(&s1[r], a0[c] * 0.6931471805599453f);  // ln 2
}

// ---------------- k3: a1 = a0+s1; ws1 direct (wave == 64-word) ----------------
__global__ __launch_bounds__(256) void a1_ws(
    const float* __restrict__ a0, const float* __restrict__ s1,
    float* __restrict__ a1, float* __restrict__ ws1) {
  int t = threadIdx.x, i = blockIdx.x * 256 + t;
  float v = a0[i] + s1[i];
  a1[i] = v;
  float s = wave_sum64(v);
  if ((t & 63) == 0) ws1[i >> 6] = s;
}

// ---------------- hop machinery ----------------
// Stage v[4096] into LDS with stride-65 64-float segments: gather address
// (lane*65+b) -> bank (lane+b)%32: 2-way for any uniform b (free, m136).
__device__ __forceinline__ void stage_v(const float* __restrict__ v,
                                        float* __restrict__ vl, int t) {
#pragma unroll
  for (int u = 0; u < 16; ++u) {
    int j = t + u * 256;
    vl[(j >> 6) * 65 + (j & 63)] = v[j];
  }
}

// One wave per row i (lane = word). Compact neighbor indices to LDS, then
// 8-wide pipelined OR-gather of SRC rows (coalesced 512B each).
__device__ __forceinline__ unsigned long long gather_row(
    const unsigned long long* __restrict__ Arow,
    const unsigned long long* __restrict__ SRC,
    int i, int lane, unsigned short* __restrict__ nbr, int* __restrict__ ncnt) {
  if (lane == 0) *ncnt = 0;
  unsigned long long rw = Arow[(size_t)i * WPR + lane];
  int c = __popcll(rw);
  int base = 0;
  if (c) base = atomicAdd(ncnt, c);
  while (rw) {
    int b = __builtin_ctzll(rw);
    rw &= rw - 1ull;
    if (base < MAXN) nbr[base] = (unsigned short)((lane << 6) + b);
    ++base;
  }
  int cnt = *ncnt;  // wave-lockstep: same-wave LDS ops retire in order
  cnt = cnt < MAXN ? cnt : MAXN;
  unsigned long long acc = 0ull;
  int j = 0;
  for (; j + 8 <= cnt; j += 8) {
    unsigned long long v0 = SRC[(size_t)nbr[j + 0] * WPR + lane];
    unsigned long long v1 = SRC[(size_t)nbr[j + 1] * WPR + lane];
    unsigned long long v2 = SRC[(size_t)nbr[j + 2] * WPR + lane];
    unsigned long long v3 = SRC[(size_t)nbr[j + 3] * WPR + lane];
    unsigned long long v4 = SRC[(size_t)nbr[j + 4] * WPR + lane];
    unsigned long long v5 = SRC[(size_t)nbr[j + 5] * WPR + lane];
    unsigned long long v6 = SRC[(size_t)nbr[j + 6] * WPR + lane];
    unsigned long long v7 = SRC[(size_t)nbr[j + 7] * WPR + lane];
    acc |= ((v0 | v1) | (v2 | v3)) | ((v4 | v5) | (v6 | v7));
  }
  for (; j < cnt; ++j) acc |= SRC[(size_t)nbr[j] * WPR + lane];
  return acc;
}

// Masked dot vs LDS-staged v (stride 65); complement trick for dense words.
__device__ __forceinline__ float masked_dot(
    unsigned long long m, const float* __restrict__ vl,
    const float* __restrict__ wsum, int lane) {
  int cnt = __popcll(m);
  bool inv = cnt > 32;
  unsigned long long it = inv ? ~m : m;
  float part = inv ? wsum[lane] : 0.f;
  float sgn = inv ? -1.f : 1.f;
  const float* p = vl + lane * 65;
  float acc = 0.f;
  while (it) {
    int b = __builtin_ctzll(it);
    it &= it - 1ull;
    acc += p[b];
  }
  return fmaf(sgn, acc, part);
}

// ---------------- k4: hop 2 ----------------
__global__ __launch_bounds__(256) void hop2(
    const unsigned long long* __restrict__ A, unsigned long long* __restrict__ A2,
    const float* __restrict__ a1, const float* __restrict__ ws1,
    const float* __restrict__ s1, float* __restrict__ s2, float* __restrict__ a2,
    float* __restrict__ ws2) {
  __shared__ float vl[64 * 65];
  __shared__ unsigned short nbr[4][MAXN];
  __shared__ int ncnt[4];
  int t = threadIdx.x, wave = t >> 6, lane = t & 63;
  stage_v(a1, vl, t);
  __syncthreads();
  int i = blockIdx.x * 4 + wave;
  unsigned long long acc = gather_row(A, A, i, lane, nbr[wave], &ncnt[wave]);
  A2[(size_t)i * WPR + lane] = acc;
  float part = masked_dot(acc, vl, ws1, lane);
  part = wave_sum64(part);
  if (lane == 0) {
    float s2v = fmaf(1.0986122886681098f, part, s1[i]);  // + ln3 * t2
    s2[i] = s2v;
    float a2v = a1[i] + s2v;
    a2[i] = a2v;
    atomicAdd(&ws2[i >> 6], a2v);
  }
}

// ---------------- k5: hop 3 (A3 never materialized) ----------------
__global__ __launch_bounds__(256) void hop3(
    const unsigned long long* __restrict__ A, const unsigned long long* __restrict__ A2,
    const float* __restrict__ a2, const float* __restrict__ ws2,
    const float* __restrict__ s2, float* __restrict__ out) {
  __shared__ float vl[64 * 65];
  __shared__ unsigned short nbr[4][MAXN];
  __shared__ int ncnt[4];
  int t = threadIdx.x, wave = t >> 6, lane = t & 63;
  stage_v(a2, vl, t);
  __syncthreads();
  int i = blockIdx.x * 4 + wave;
  unsigned long long acc = gather_row(A, A2, i, lane, nbr[wave], &ncnt[wave]);
  float part = masked_dot(acc, vl, ws2, lane);
  part = wave_sum64(part);
  if (lane == 0)
    out[i] = a2[i] + fmaf(1.3862943611198906f, part, s2[i]);  // + ln4 * t3
}

extern "C" void kernel_launch(void* const* d_in, const int* in_sizes, int n_in,
                              void* d_out, int out_size, void* d_ws, size_t ws_size,
                              hipStream_t stream) {
  const float* coeffs = (const float*)d_in[0];
  const int*   edge   = (const int*)d_in[1];  // [2, NE] int32
  const float* W0 = (const float*)d_in[2];
  const float* b0 = (const float*)d_in[3];
  const float* W1 = (const float*)d_in[4];
  const float* W2 = (const float*)d_in[5];
  const float* W3 = (const float*)d_in[6];
  const float* b3 = (const float*)d_in[7];
  float* out = (float*)d_out;

  char* ws = (char*)d_ws;
  unsigned long long* A  = (unsigned long long*)ws;                // 2 MB
  unsigned long long* A2 = (unsigned long long*)(ws + (2u << 20)); // 2 MB
  float* f   = (float*)(ws + (4u << 20));
  float* a0v = f;
  float* a1v = f + 4096;
  float* s1  = f + 8192;
  float* s2  = f + 12288;
  float* a2v = f + 16384;
  float* ws1 = f + 20480;  // 64
  float* ws2 = f + 20544;  // 64
  short* Wp  = (short*)(ws + (4u << 20) + 128 * 1024);  // 192 KB packed weights

  pack_w<<<24, 256, 0, stream>>>(W0, W1, W2, Wp);
  mlp_mfma<<<NN / 8, 256, 0, stream>>>(coeffs, Wp, b0, W3, b3, a0v, A, s1, ws2);
  build_graph<<<NE / 256, 256, 0, stream>>>(edge, edge + NE, a0v, A, s1);
  a1_ws<<<NN / 256, 256, 0, stream>>>(a0v, s1, a1v, ws1);
  hop2<<<NN / 4, 256, 0, stream>>>(A, A2, a1v, ws1, s1, s2, a2v, ws2);
  hop3<<<NN / 4, 256, 0, stream>>>(A, A2, a2v, ws2, s2, out);
}

// Round 6
// 117.408 us; speedup vs baseline: 1.2060x; 1.2060x over previous
//
#include <hip/hip_runtime.h>
#include <cstdint>
#include <cstddef>

// RoGPE node encoder. 5 kernels:
//  k0 pack_w: W0/W1/W2 -> bf16 hi/lo MFMA B-fragments (coalesced 16B/lane)
//  k1 mlp_mfma: zero A/s1 + 3-layer MLP, bf16 hi/lo split MFMA (3-term
//     compensation). R6: per-layer B loads register-blocked (16 short8 held
//     live -> one vmcnt drain, not 16 serialized round-trips; R4/R5 ran at
//     VGPR_Count=52 which forced load->use serialization = ~95% stall),
//     __launch_bounds__(256,2) for a 256-VGPR budget.
//  k2 build_graph: s1[r] += ln2*a0[c] (dupes kept), A bitset atomicOr
//  k3 hop2: stage vl=a0+s1 (a1) + per-word sums in LDS; A2 row = OR of
//     neighbor A rows; s2 = s1+ln3*(A2@a1); a2 = a1+s2
//  k4 hop3: stage vl=a2 + per-word sums in LDS; A3 row on the fly from A2;
//     out = a2 + s2 + ln4*(A3@a2)

constexpr int NN   = 4096;
constexpr int D    = 128;
constexpr int NE   = 131072;
constexpr int WPR  = 64;    // u64 words per bitset row
constexpr int MAXN = 256;   // neighbor-list cap (deg ~Binom, mean 32, max ~64)

typedef __attribute__((ext_vector_type(8))) short  short8;
typedef __attribute__((ext_vector_type(4))) float  float4v;

__device__ __forceinline__ unsigned short f32_bf16(float x) {
  unsigned u = __float_as_uint(x);
  return (unsigned short)((u + 0x7FFFu + ((u >> 16) & 1u)) >> 16);  // RNE
}
__device__ __forceinline__ float bf16_f32(unsigned short b) {
  return __uint_as_float(((unsigned)b) << 16);
}

struct Frag { short8 hi; short8 lo; };

// two float4s -> bf16 hi/lo split fragment
__device__ __forceinline__ Frag mk_frag(float4v a, float4v b) {
  Frag f;
#pragma unroll
  for (int j = 0; j < 4; ++j) {
    float x = a[j];
    unsigned short h = f32_bf16(x);
    f.hi[j] = (short)h;
    f.lo[j] = (short)f32_bf16(x - bf16_f32(h));
    float y = b[j];
    unsigned short h2 = f32_bf16(y);
    f.hi[j + 4] = (short)h2;
    f.lo[j + 4] = (short)f32_bf16(y - bf16_f32(h2));
  }
  return f;
}
__device__ __forceinline__ Frag split8(const float* __restrict__ p) {
  return mk_frag(*(const float4v*)p, *(const float4v*)(p + 4));
}

// 3-term compensated product (lo*lo dropped; measured identical absmax)
__device__ __forceinline__ float4v mfma3(const Frag& A, const Frag& B, float4v c) {
  c = __builtin_amdgcn_mfma_f32_16x16x32_bf16(A.lo, B.hi, c, 0, 0, 0);
  c = __builtin_amdgcn_mfma_f32_16x16x32_bf16(A.hi, B.lo, c, 0, 0, 0);
  c = __builtin_amdgcn_mfma_f32_16x16x32_bf16(A.hi, B.hi, c, 0, 0, 0);
  return c;
}

__device__ __forceinline__ float wave_sum64(float v) {
#pragma unroll
  for (int off = 32; off >= 1; off >>= 1) v += __shfl_xor(v, off, 64);
  return v;
}

// ---------------- k0: pack weights into MFMA B-fragments ----------------
// Fragment block (L, o, kt) = 1024 shorts: [0..511] hi (lane*8), [512..1023] lo.
// B-frag element: W_L[(o*16 + l16)*128 + kt*32 + quad*8 + j], j=0..7.
__global__ __launch_bounds__(256) void pack_w(
    const float* __restrict__ W0, const float* __restrict__ W1,
    const float* __restrict__ W2, short* __restrict__ Wp) {
  int tid = blockIdx.x * 256 + threadIdx.x;  // 6144 total
  int lane = tid & 63, kt = (tid >> 6) & 3, o = (tid >> 8) & 7, L = tid >> 11;
  int quad = lane >> 4, l16 = lane & 15;
  const float* W = (L == 0) ? W0 : (L == 1) ? W1 : W2;
  Frag f = split8(W + (size_t)(o * 16 + l16) * D + kt * 32 + quad * 8);
  short* base = Wp + (size_t)(((L * 8 + o) * 4) + kt) * 1024;
  *(short8*)(base + lane * 8) = f.hi;
  *(short8*)(base + 512 + lane * 8) = f.lo;
}

// ---------------- k1: zero-init + MFMA MLP ----------------
// 512 blocks x 256 threads, 8 nodes/block (A rows 8..15 dup 0..7, free).
// A-frag: A[m=lane&15][k=quad*8+j]; B-frag from packed Wp; C/D: row=quad*4+reg,
// col=lane&15. Per layer: ALL B loads issued into held registers, then MFMA.
__global__ __launch_bounds__(256, 2) void mlp_mfma(
    const float* __restrict__ coeffs, const short* __restrict__ Wp,
    const float* __restrict__ b0,
    const float* __restrict__ W3, const float* __restrict__ b3,
    float* __restrict__ a0v,
    unsigned long long* __restrict__ A, float* __restrict__ s1) {
  __shared__ float hbuf[16 * 132];
  __shared__ float psh[4][16];
  const int b = blockIdx.x, t = threadIdx.x;
  const int wave = t >> 6, lane = t & 63;
  const int quad = lane >> 4, l16 = lane & 15;
  const int node0 = b * 8;
  const int ot0 = 2 * wave, ot1 = 2 * wave + 1;

  // zero A slice (4 KB/block) + s1 slice (8 f)
  {
    float4v z4 = {0.f, 0.f, 0.f, 0.f};
    ((float4v*)A)[(size_t)b * 256 + t] = z4;
    if (t < 2) ((float4v*)(s1 + node0))[t] = z4;
  }

  float4v r0, r1;
#pragma unroll
  for (int L = 0; L < 3; ++L) {
    // ---- issue ALL 16 B-fragment loads (held live; one vmcnt drain) ----
    const short* WL = Wp + (size_t)L * 32768;
    short8 Bf[4][4];
#pragma unroll
    for (int kt = 0; kt < 4; ++kt) {
      const short* p0 = WL + (size_t)(ot0 * 4 + kt) * 1024 + lane * 8;
      const short* p1 = WL + (size_t)(ot1 * 4 + kt) * 1024 + lane * 8;
      Bf[kt][0] = *(const short8*)p0;
      Bf[kt][1] = *(const short8*)(p0 + 512);
      Bf[kt][2] = *(const short8*)p1;
      Bf[kt][3] = *(const short8*)(p1 + 512);
    }
    // ---- A fragments: raw loads first, then convert ----
    Frag Af[4];
    if (L == 0) {
      const float* abase = coeffs + (size_t)(node0 + (l16 & 7)) * D + quad * 8;
      float4v araw[8];
#pragma unroll
      for (int kt = 0; kt < 4; ++kt) {
        araw[2 * kt]     = *(const float4v*)(abase + kt * 32);
        araw[2 * kt + 1] = *(const float4v*)(abase + kt * 32 + 4);
      }
#pragma unroll
      for (int kt = 0; kt < 4; ++kt) Af[kt] = mk_frag(araw[2 * kt], araw[2 * kt + 1]);
    } else {
      const float* abase = hbuf + (l16 & 7) * 132 + quad * 8;
#pragma unroll
      for (int kt = 0; kt < 4; ++kt) Af[kt] = split8(abase + kt * 32);
    }
    // ---- MFMA chain ----
    float4v acc0 = {0.f, 0.f, 0.f, 0.f}, acc1 = acc0;
#pragma unroll
    for (int kt = 0; kt < 4; ++kt) {
      Frag B0; B0.hi = Bf[kt][0]; B0.lo = Bf[kt][1];
      Frag B1; B1.hi = Bf[kt][2]; B1.lo = Bf[kt][3];
      acc0 = mfma3(Af[kt], B0, acc0);
      acc1 = mfma3(Af[kt], B1, acc1);
    }
    if (L == 0) {
      float ba = b0[ot0 * 16 + l16], bb = b0[ot1 * 16 + l16];
#pragma unroll
      for (int j = 0; j < 4; ++j) { acc0[j] += ba; acc1[j] += bb; }
    }
#pragma unroll
    for (int j = 0; j < 4; ++j) {
      acc0[j] = fmaxf(acc0[j], 0.f);
      acc1[j] = fmaxf(acc1[j], 0.f);
    }
    if (L < 2) {
      __syncthreads();  // all hbuf A-frag reads done before overwrite
#pragma unroll
      for (int j = 0; j < 4; ++j) {
        hbuf[(quad * 4 + j) * 132 + ot0 * 16 + l16] = acc0[j];
        hbuf[(quad * 4 + j) * 132 + ot1 * 16 + l16] = acc1[j];
      }
      __syncthreads();
    } else {
      r0 = acc0; r1 = acc1;
    }
  }
  // fused 128->1 dot with W3
  float w3a = W3[ot0 * 16 + l16], w3b = W3[ot1 * 16 + l16];
#pragma unroll
  for (int j = 0; j < 4; ++j) {
    float v = fmaf(r0[j], w3a, r1[j] * w3b);
#pragma unroll
    for (int off = 1; off <= 8; off <<= 1) v += __shfl_xor(v, off, 64);
    if (l16 == 0) psh[wave][quad * 4 + j] = v;
  }
  __syncthreads();
  if (t < 8)
    a0v[node0 + t] = psh[0][t] + psh[1][t] + psh[2][t] + psh[3][t] + b3[0];
}

// ---------------- k2: bitset adjacency + hop-1 scatter ----------------
__global__ __launch_bounds__(256) void build_graph(
    const int* __restrict__ er, const int* __restrict__ ec,
    const float* __restrict__ a0, unsigned long long* __restrict__ A,
    float* __restrict__ s1) {
  int e = blockIdx.x * 256 + threadIdx.x;
  if (e >= NE) return;
  int r = er[e] & (NN - 1);
  int c = ec[e] & (NN - 1);
  atomicOr(&A[(size_t)r * WPR + (c >> 6)], 1ull << (c & 63));
  atomicAdd(&s1[r], a0[c] * 0.6931471805599453f);  // ln 2
}

// ---------------- hop machinery ----------------
// One wave per row i (lane = word). Compact neighbor indices to LDS, then
// 8-wide pipelined OR-gather of SRC rows (coalesced 512B each).
__device__ __forceinline__ unsigned long long gather_row(
    const unsigned long long* __restrict__ Arow,
    const unsigned long long* __restrict__ SRC,
    int i, int lane, unsigned short* __restrict__ nbr, int* __restrict__ ncnt) {
  if (lane == 0) *ncnt = 0;
  unsigned long long rw = Arow[(size_t)i * WPR + lane];
  int c = __popcll(rw);
  int base = 0;
  if (c) base = atomicAdd(ncnt, c);
  while (rw) {
    int b = __builtin_ctzll(rw);
    rw &= rw - 1ull;
    if (base < MAXN) nbr[base] = (unsigned short)((lane << 6) + b);
    ++base;
  }
  int cnt = *ncnt;  // wave-lockstep: same-wave LDS ops retire in order
  cnt = cnt < MAXN ? cnt : MAXN;
  unsigned long long acc = 0ull;
  int j = 0;
  for (; j + 8 <= cnt; j += 8) {
    unsigned long long v0 = SRC[(size_t)nbr[j + 0] * WPR + lane];
    unsigned long long v1 = SRC[(size_t)nbr[j + 1] * WPR + lane];
    unsigned long long v2 = SRC[(size_t)nbr[j + 2] * WPR + lane];
    unsigned long long v3 = SRC[(size_t)nbr[j + 3] * WPR + lane];
    unsigned long long v4 = SRC[(size_t)nbr[j + 4] * WPR + lane];
    unsigned long long v5 = SRC[(size_t)nbr[j + 5] * WPR + lane];
    unsigned long long v6 = SRC[(size_t)nbr[j + 6] * WPR + lane];
    unsigned long long v7 = SRC[(size_t)nbr[j + 7] * WPR + lane];
    acc |= ((v0 | v1) | (v2 | v3)) | ((v4 | v5) | (v6 | v7));
  }
  for (; j < cnt; ++j) acc |= SRC[(size_t)nbr[j] * WPR + lane];
  return acc;
}

// Masked dot vs LDS-staged v (stride 65: bank (lane+b)%32, 2-way = free);
// complement trick for dense words.
__device__ __forceinline__ float masked_dot(
    unsigned long long m, const float* __restrict__ vl,
    const float* __restrict__ wsum, int lane) {
  int cnt = __popcll(m);
  bool inv = cnt > 32;
  unsigned long long it = inv ? ~m : m;
  float part = inv ? wsum[lane] : 0.f;
  float sgn = inv ? -1.f : 1.f;
  const float* p = vl + lane * 65;
  float acc = 0.f;
  while (it) {
    int b = __builtin_ctzll(it);
    it &= it - 1ull;
    acc += p[b];
  }
  return fmaf(sgn, acc, part);
}

// per-block word sums of staged vl -> wsm[64] (t<64: 64 LDS reads, 2-way free)
__device__ __forceinline__ void word_sums(const float* __restrict__ vl,
                                          float* __restrict__ wsm, int t) {
  if (t < 64) {
    float s = 0.f;
    const float* p = vl + t * 65;
#pragma unroll 16
    for (int b2 = 0; b2 < 64; ++b2) s += p[b2];
    wsm[t] = s;
  }
}

// ---------------- k3: hop 2 (a1/ws1 computed in-block from a0,s1) ----------------
__global__ __launch_bounds__(256) void hop2(
    const unsigned long long* __restrict__ A, unsigned long long* __restrict__ A2,
    const float* __restrict__ a0, const float* __restrict__ s1,
    float* __restrict__ s2, float* __restrict__ a2) {
  __shared__ float vl[64 * 65];
  __shared__ float wsm[64];
  __shared__ unsigned short nbr[4][MAXN];
  __shared__ int ncnt[4];
  int t = threadIdx.x, wave = t >> 6, lane = t & 63;
#pragma unroll
  for (int u = 0; u < 16; ++u) {
    int j = t + u * 256;
    vl[(j >> 6) * 65 + (j & 63)] = a0[j] + s1[j];  // a1
  }
  __syncthreads();
  word_sums(vl, wsm, t);
  __syncthreads();
  int i = blockIdx.x * 4 + wave;
  unsigned long long acc = gather_row(A, A, i, lane, nbr[wave], &ncnt[wave]);
  A2[(size_t)i * WPR + lane] = acc;
  float part = masked_dot(acc, vl, wsm, lane);
  part = wave_sum64(part);
  if (lane == 0) {
    float s2v = fmaf(1.0986122886681098f, part, s1[i]);  // + ln3 * t2
    s2[i] = s2v;
    a2[i] = vl[(i >> 6) * 65 + (i & 63)] + s2v;          // a1[i] + s2
  }
}

// ---------------- k4: hop 3 (A3 never materialized; ws2 in-block) ----------------
__global__ __launch_bounds__(256) void hop3(
    const unsigned long long* __restrict__ A, const unsigned long long* __restrict__ A2,
    const float* __restrict__ a2, const float* __restrict__ s2,
    float* __restrict__ out) {
  __shared__ float vl[64 * 65];
  __shared__ float wsm[64];
  __shared__ unsigned short nbr[4][MAXN];
  __shared__ int ncnt[4];
  int t = threadIdx.x, wave = t >> 6, lane = t & 63;
#pragma unroll
  for (int u = 0; u < 16; ++u) {
    int j = t + u * 256;
    vl[(j >> 6) * 65 + (j & 63)] = a2[j];
  }
  __syncthreads();
  word_sums(vl, wsm, t);
  __syncthreads();
  int i = blockIdx.x * 4 + wave;
  unsigned long long acc = gather_row(A, A2, i, lane, nbr[wave], &ncnt[wave]);
  float part = masked_dot(acc, vl, wsm, lane);
  part = wave_sum64(part);
  if (lane == 0)
    out[i] = vl[(i >> 6) * 65 + (i & 63)] +
             fmaf(1.3862943611198906f, part, s2[i]);  // a2 + s2 + ln4*t3
}

extern "C" void kernel_launch(void* const* d_in, const int* in_sizes, int n_in,
                              void* d_out, int out_size, void* d_ws, size_t ws_size,
                              hipStream_t stream) {
  const float* coeffs = (const float*)d_in[0];
  const int*   edge   = (const int*)d_in[1];  // [2, NE] int32
  const float* W0 = (const float*)d_in[2];
  const float* b0 = (const float*)d_in[3];
  const float* W1 = (const float*)d_in[4];
  const float* W2 = (const float*)d_in[5];
  const float* W3 = (const float*)d_in[6];
  const float* b3 = (const float*)d_in[7];
  float* out = (float*)d_out;

  char* ws = (char*)d_ws;
  unsigned long long* A  = (unsigned long long*)ws;                // 2 MB
  unsigned long long* A2 = (unsigned long long*)(ws + (2u << 20)); // 2 MB
  float* f   = (float*)(ws + (4u << 20));
  float* a0v = f;
  float* s1  = f + 4096;
  float* s2  = f + 8192;
  float* a2v = f + 12288;
  short* Wp  = (short*)(ws + (4u << 20) + 128 * 1024);  // 192 KB packed weights

  pack_w<<<24, 256, 0, stream>>>(W0, W1, W2, Wp);
  mlp_mfma<<<NN / 8, 256, 0, stream>>>(coeffs, Wp, b0, W3, b3, a0v, A, s1);
  build_graph<<<NE / 256, 256, 0, stream>>>(edge, edge + NE, a0v, A, s1);
  hop2<<<NN / 4, 256, 0, stream>>>(A, A2, a0v, s1, s2, a2v);
  hop3<<<NN / 4, 256, 0, stream>>>(A, A2, a2v, s2, out);
}